// Round 4
// baseline (3440.070 us; speedup 1.0000x reference)
//
#include <hip/hip_runtime.h>

typedef unsigned short u16;
typedef __attribute__((ext_vector_type(4))) float f32x4;
typedef __attribute__((ext_vector_type(8))) __bf16 bf16x8;
typedef __attribute__((ext_vector_type(8))) u16 u16x8;
typedef __attribute__((ext_vector_type(4))) int i32x4;

#define MFMA(a, b, c) __builtin_amdgcn_mfma_f32_16x16x32_bf16(a, b, c, 0, 0, 0)

__device__ __forceinline__ u16 f2bf(float f) {
  union { float f; unsigned u; } v; v.f = f;
  unsigned r = v.u + 0x7FFFu + ((v.u >> 16) & 1u);
  return (u16)(r >> 16);
}
__device__ __forceinline__ float bf2f(u16 b) {
  union { unsigned u; float f; } v; v.u = ((unsigned)b) << 16; return v.f;
}
__device__ __forceinline__ float sigm(float x) { return 1.f / (1.f + __expf(-x)); }
__device__ __forceinline__ float tanh_(float x) {
  float e = __expf(-2.f * fabsf(x));
  float r = (1.f - e) / (1.f + e);
  return x < 0.f ? -r : r;
}

// ---------------------------------------------------------------------------
// cvt_bf16: f32 -> bf16 (used for Whh, Wih, W1, W2)
// ---------------------------------------------------------------------------
__global__ __launch_bounds__(256) void cvt_bf16(const float* __restrict__ src,
                                                u16* __restrict__ dst, int n8) {
  int i = blockIdx.x * 256 + threadIdx.x;
  if (i >= n8) return;
  int e = i * 8;
  u16x8 o;
#pragma unroll
  for (int j = 0; j < 8; ++j) o[j] = f2bf(src[e + j]);
  *(u16x8*)(dst + e) = o;
}

// ---------------------------------------------------------------------------
// xp_gemm: xp[(dir*65536 + s*8 + t)][g] = win[s][widx(s,t,dir)] . Wih[g] + bih[g]
// M=65536 gathered rows, K=512, N=1536. 128x128 tile, 256 threads, bf16 out.
// widx: fwd = 8-len_f+t (in [0,14]); bwd = 6+len_b-t (in [0,14]). No clip
// needed; rows with t>=len produce don't-care values (masked in recurrence).
// ---------------------------------------------------------------------------
__global__ __launch_bounds__(256) void xp_gemm(const float* __restrict__ win,
                                               const int* __restrict__ wlen,
                                               const u16* __restrict__ Wihb,
                                               const float* __restrict__ bih,
                                               u16* __restrict__ xp, int dir) {
  __shared__ u16 As[128 * 64], Bs[128 * 64];
  const int tid = threadIdx.x;
  const int wave = tid >> 6, lane = tid & 63;
  const int ln = lane & 15, ks = lane >> 4;
  const int wm = wave & 1, wn = wave >> 1;
  const int m0 = blockIdx.x * 128, n0 = blockIdx.y * 128;

  // row-gather setup: this thread stages row r = tid>>1 of the A tile
  const int r = tid >> 1, hh = tid & 1;
  const int m = m0 + r;        // global row = s*8 + t
  const int s = m >> 3, tt = m & 7;
  const int wl = wlen[s];
  const int len = dir ? (wl / 2 + 1) : ((wl - 1) / 2 + 1);
  const int widx = dir ? (6 + len - tt) : (8 - len + tt);
  const float* arow = win + ((size_t)s * 15 + widx) * 512;

  f32x4 acc[4][4];
#pragma unroll
  for (int mt = 0; mt < 4; ++mt)
#pragma unroll
    for (int nt = 0; nt < 4; ++nt)
#pragma unroll
      for (int j = 0; j < 4; ++j) acc[mt][nt][j] = 0.f;

  for (int k0 = 0; k0 < 512; k0 += 64) {
    // A: gather + f32->bf16
    {
      const float* srcp = arow + k0 + hh * 32;
      u16* dst = As + r * 64 + hh * 32;
#pragma unroll
      for (int i = 0; i < 4; ++i) {
        f32x4 v0 = __builtin_nontemporal_load((const f32x4*)(srcp + i * 8));
        f32x4 v1 = __builtin_nontemporal_load((const f32x4*)(srcp + i * 8 + 4));
        u16x8 o;
        o[0] = f2bf(v0[0]); o[1] = f2bf(v0[1]); o[2] = f2bf(v0[2]); o[3] = f2bf(v0[3]);
        o[4] = f2bf(v1[0]); o[5] = f2bf(v1[1]); o[6] = f2bf(v1[2]); o[7] = f2bf(v1[3]);
        *(u16x8*)(dst + i * 8) = o;
      }
    }
    // B: bf16 rows of Wihb
    {
      const i32x4* sb = (const i32x4*)(Wihb + (size_t)(n0 + r) * 512 + k0 + hh * 32);
      i32x4* db = (i32x4*)(Bs + r * 64 + hh * 32);
#pragma unroll
      for (int i = 0; i < 4; ++i) db[i] = sb[i];
    }
    __syncthreads();
#pragma unroll
    for (int kk = 0; kk < 2; ++kk) {
      bf16x8 af[4], bfm[4];
#pragma unroll
      for (int mt = 0; mt < 4; ++mt)
        af[mt] = *(const bf16x8*)(As + (wm * 64 + mt * 16 + ln) * 64 + kk * 32 + ks * 8);
#pragma unroll
      for (int nt = 0; nt < 4; ++nt)
        bfm[nt] = *(const bf16x8*)(Bs + (wn * 64 + nt * 16 + ln) * 64 + kk * 32 + ks * 8);
#pragma unroll
      for (int mt = 0; mt < 4; ++mt)
#pragma unroll
        for (int nt = 0; nt < 4; ++nt) acc[mt][nt] = MFMA(af[mt], bfm[nt], acc[mt][nt]);
    }
    __syncthreads();
  }

#pragma unroll
  for (int nt = 0; nt < 4; ++nt) {
    const int col = n0 + wn * 64 + nt * 16 + ln;
    const float bv = bih[col];
#pragma unroll
    for (int mt = 0; mt < 4; ++mt)
#pragma unroll
      for (int j = 0; j < 4; ++j) {
        const int rowm = m0 + wm * 64 + mt * 16 + ks * 4 + j;
        float v = acc[mt][nt][j] + bv;
        __builtin_nontemporal_store(
            f2bf(v), xp + ((size_t)dir * 65536 + rowm) * 1536 + col);
      }
  }
}

// ---------------------------------------------------------------------------
// gru_rec: recurrent h-half only. 256 blocks x 512 threads (8 waves).
//   dir = blockIdx & 1, grp = blockIdx >> 1 (64 samples).
// Per step t: gh = h(64x512) @ Whh^T(512x1536); 4 N-quarter passes x 8 waves;
// acc = 48 f32/lane. xp (precomputed, includes bih) loaded per-element in the
// epilogue. h double-buffered in LDS -> writes go to the other buffer -> no
// register holding, ONE barrier per step. Weight array 1.5 MB/dir (L2-fit).
// Freeze: rows with t >= len copy h. Final h in hb[bmax&1].
// ---------------------------------------------------------------------------
#define LROW 520  // padded LDS row stride (bf16) to break bank conflicts

__global__ __launch_bounds__(512)
__attribute__((amdgpu_waves_per_eu(2, 2))) void gru_rec(
    const int* __restrict__ wlen, const u16* __restrict__ Whhb_f,
    const u16* __restrict__ Whhb_b, const float* __restrict__ bhh_f,
    const float* __restrict__ bhh_b, const u16* __restrict__ xp,
    u16* __restrict__ hcat) {
  extern __shared__ char smem[];
  u16* hb0 = (u16*)smem;              // [64][LROW]
  u16* hb1 = hb0 + 64 * LROW;         // [64][LROW]
  int* len_s = (int*)(hb1 + 64 * LROW);
  int* bmax_s = len_s + 64;

  const int dir = blockIdx.x & 1;
  const int grp = blockIdx.x >> 1;
  const int s0 = grp * 64;
  const u16* W = dir ? Whhb_b : Whhb_f;
  const float* bhh = dir ? bhh_b : bhh_f;
  const u16* xpd = xp + (size_t)dir * 65536 * 1536;

  const int tid = threadIdx.x;
  const int wave = tid >> 6;
  const int lane = tid & 63;
  const int ln = lane & 15;
  const int ks = lane >> 4;  // 0..3

  // ---- init: zero hb0, lengths + block max ----
  if (tid == 0) *bmax_s = 0;
  for (int i = tid; i < 64 * LROW / 8; i += 512) ((u16x8*)hb0)[i] = (u16x8)0;
  __syncthreads();
  if (tid < 64) {
    int wl = wlen[s0 + tid];
    int len = dir ? (wl / 2 + 1) : ((wl - 1) / 2 + 1);
    len_s[tid] = len;
    atomicMax(bmax_s, len);
  }
  __syncthreads();
  const int bmax = *bmax_s;

  // ---- recurrent biases (bih folded into xp) ----
  float b_r[4], b_z[4], b_hn[4];
#pragma unroll
  for (int p = 0; p < 4; ++p) {
    int d = (p * 8 + wave) * 16 + ln;
    b_r[p] = bhh[d];
    b_z[p] = bhh[512 + d];
    b_hn[p] = bhh[1024 + d];
  }

  for (int t = 0; t < bmax; ++t) {
    u16* h_cur = (t & 1) ? hb1 : hb0;
    u16* h_nxt = (t & 1) ? hb0 : hb1;

#pragma unroll
    for (int p = 0; p < 4; ++p) {
      const int dcol = (p * 8 + wave) * 16 + ln;
      const u16* wrow = W + (size_t)dcol * 512;

      f32x4 accr[4], accz[4], acchn[4];
#pragma unroll
      for (int mt = 0; mt < 4; ++mt)
#pragma unroll
        for (int j = 0; j < 4; ++j) {
          accr[mt][j] = 0.f; accz[mt][j] = 0.f; acchn[mt][j] = 0.f;
        }

#pragma unroll
      for (int kk = 0; kk < 16; ++kk) {
        const int krel = kk * 32 + ks * 8;
        bf16x8 a[4];
#pragma unroll
        for (int mt = 0; mt < 4; ++mt)
          a[mt] = *(const bf16x8*)(h_cur + (mt * 16 + ln) * LROW + krel);
        bf16x8 br = *(const bf16x8*)(wrow + krel);
        bf16x8 bz = *(const bf16x8*)(wrow + 512 * 512 + krel);
        bf16x8 bn = *(const bf16x8*)(wrow + 1024 * 512 + krel);
#pragma unroll
        for (int mt = 0; mt < 4; ++mt) {
          accr[mt] = MFMA(a[mt], br, accr[mt]);
          accz[mt] = MFMA(a[mt], bz, accz[mt]);
          acchn[mt] = MFMA(a[mt], bn, acchn[mt]);
        }
      }

      // epilogue: xp loads + nonlinearity; write to the OTHER buffer
#pragma unroll
      for (int mt = 0; mt < 4; ++mt)
#pragma unroll
        for (int j = 0; j < 4; ++j) {
          const int row = mt * 16 + ks * 4 + j;
          const u16* xq = xpd + ((size_t)(s0 + row) * 8 + t) * 1536 + dcol;
          float xr = bf2f(__builtin_nontemporal_load(xq));
          float xz = bf2f(__builtin_nontemporal_load(xq + 512));
          float xn = bf2f(__builtin_nontemporal_load(xq + 1024));
          float rr = sigm(accr[mt][j] + b_r[p] + xr);
          float zz = sigm(accz[mt][j] + b_z[p] + xz);
          float nn = tanh_(xn + rr * (acchn[mt][j] + b_hn[p]));
          float hold = bf2f(h_cur[row * LROW + dcol]);
          float hnew = (t < len_s[row]) ? ((1.f - zz) * nn + zz * hold) : hold;
          h_nxt[row * LROW + dcol] = f2bf(hnew);
        }
    }  // passes
    __syncthreads();  // h_nxt complete before it becomes h_cur
  }    // t

  // ---- write final h to hcat[s][dir*512 + k] ----
  const u16* hf = (bmax & 1) ? hb1 : hb0;
  const int xrow = tid >> 3;
  const int xcol = tid & 7;
#pragma unroll
  for (int i = 0; i < 8; ++i) {
    int off = xcol * 8 + i * 64;
    u16x8 v = *(const u16x8*)(hf + xrow * LROW + off);
    __builtin_nontemporal_store(
        v, (u16x8*)(hcat + (size_t)(s0 + xrow) * 1024 + dir * 512 + off));
  }
}

// ---------------------------------------------------------------------------
// FALLBACK path (used when workspace < 416 MiB): round-2 fused kernel.
// ---------------------------------------------------------------------------
__global__ __launch_bounds__(256) void build_wcat(const float* __restrict__ Whh,
                                                  const float* __restrict__ Wih,
                                                  u16* __restrict__ Wcat) {
  int i = blockIdx.x * 256 + threadIdx.x;
  if (i >= 1536 * 1024 / 8) return;
  int e = i * 8;
  int g = e >> 10, k = e & 1023;
  const float* src = (k < 512) ? (Whh + g * 512 + k) : (Wih + g * 512 + (k - 512));
  u16x8 o;
#pragma unroll
  for (int j = 0; j < 8; ++j) o[j] = f2bf(src[j]);
  *(u16x8*)(Wcat + e) = o;
}

__global__ __launch_bounds__(512)
__attribute__((amdgpu_waves_per_eu(2, 2))) void gru_persistent(
    const float* __restrict__ win, const int* __restrict__ wlen,
    const u16* __restrict__ Wcat_f, const u16* __restrict__ Wcat_b,
    const float* __restrict__ bih_f, const float* __restrict__ bhh_f,
    const float* __restrict__ bih_b, const float* __restrict__ bhh_b,
    u16* __restrict__ hcat) {
  extern __shared__ char smem[];
  u16* h_s = (u16*)smem;
  u16* x_s = (u16*)(smem + 64 * LROW * 2);
  int* len_s = (int*)(smem + 2 * 64 * LROW * 2);
  int* bmax_s = len_s + 64;

  const int dir = blockIdx.x & 1;
  const int grp = blockIdx.x >> 1;
  const int s0 = grp * 64;
  const u16* W = dir ? Wcat_b : Wcat_f;
  const float* bih = dir ? bih_b : bih_f;
  const float* bhh = dir ? bhh_b : bhh_f;

  const int tid = threadIdx.x;
  const int wave = tid >> 6;
  const int lane = tid & 63;
  const int ln = lane & 15;
  const int ks = lane >> 4;

  if (tid == 0) *bmax_s = 0;
  for (int i = tid; i < 64 * LROW / 8; i += 512) ((u16x8*)h_s)[i] = (u16x8)0;
  __syncthreads();
  if (tid < 64) {
    int wl = wlen[s0 + tid];
    int len = dir ? (wl / 2 + 1) : ((wl - 1) / 2 + 1);
    len_s[tid] = len;
    atomicMax(bmax_s, len);
  }
  __syncthreads();
  const int bmax = *bmax_s;

  float b_r[4], b_z[4], b_xn[4], b_hn[4];
#pragma unroll
  for (int p = 0; p < 4; ++p) {
    int d = (p * 8 + wave) * 16 + ln;
    b_r[p] = bih[d] + bhh[d];
    b_z[p] = bih[512 + d] + bhh[512 + d];
    b_xn[p] = bih[1024 + d];
    b_hn[p] = bhh[1024 + d];
  }

  const int xrow = tid >> 3;
  const int xcol = tid & 7;
  const int mylen = len_s[xrow];
  const long xbase = (long)(s0 + xrow) * 15 + (dir ? (6 + mylen) : (8 - mylen));

  for (int t = 0; t < bmax; ++t) {
    {
      long rowidx = dir ? (xbase - t) : (xbase + t);
      const float* src = win + rowidx * 512;
      u16* dst = x_s + xrow * LROW;
#pragma unroll
      for (int i = 0; i < 8; ++i) {
        int off = xcol * 8 + i * 64;
        f32x4 v0 = __builtin_nontemporal_load((const f32x4*)(src + off));
        f32x4 v1 = __builtin_nontemporal_load((const f32x4*)(src + off + 4));
        u16x8 o;
        o[0] = f2bf(v0[0]); o[1] = f2bf(v0[1]); o[2] = f2bf(v0[2]); o[3] = f2bf(v0[3]);
        o[4] = f2bf(v1[0]); o[5] = f2bf(v1[1]); o[6] = f2bf(v1[2]); o[7] = f2bf(v1[3]);
        *(u16x8*)(dst + off) = o;
      }
    }
    __syncthreads();

    unsigned holdp[3][4][2];

#pragma unroll
    for (int p = 0; p < 4; ++p) {
      const int dcol = (p * 8 + wave) * 16 + ln;
      const u16* wrow = W + (size_t)dcol * 1024;

      f32x4 accr[4], accz[4], acchn[4], accxn[4];
#pragma unroll
      for (int mt = 0; mt < 4; ++mt)
#pragma unroll
        for (int j = 0; j < 4; ++j) {
          accr[mt][j] = 0.f; accz[mt][j] = 0.f;
          acchn[mt][j] = 0.f; accxn[mt][j] = 0.f;
        }

#pragma unroll
      for (int kk = 0; kk < 16; ++kk) {
        const int krel = kk * 32 + ks * 8;
        bf16x8 a[4];
#pragma unroll
        for (int mt = 0; mt < 4; ++mt)
          a[mt] = *(const bf16x8*)(h_s + (mt * 16 + ln) * LROW + krel);
        bf16x8 br = *(const bf16x8*)(wrow + krel);
        bf16x8 bz = *(const bf16x8*)(wrow + 512 * 1024 + krel);
        bf16x8 bn = *(const bf16x8*)(wrow + 1024 * 1024 + krel);
#pragma unroll
        for (int mt = 0; mt < 4; ++mt) {
          accr[mt] = MFMA(a[mt], br, accr[mt]);
          accz[mt] = MFMA(a[mt], bz, accz[mt]);
          acchn[mt] = MFMA(a[mt], bn, acchn[mt]);
        }
      }
#pragma unroll
      for (int kk = 0; kk < 16; ++kk) {
        const int krel = kk * 32 + ks * 8;
        bf16x8 a[4];
#pragma unroll
        for (int mt = 0; mt < 4; ++mt)
          a[mt] = *(const bf16x8*)(x_s + (mt * 16 + ln) * LROW + krel);
        bf16x8 br = *(const bf16x8*)(wrow + 512 + krel);
        bf16x8 bz = *(const bf16x8*)(wrow + 512 * 1024 + 512 + krel);
        bf16x8 bn = *(const bf16x8*)(wrow + 1024 * 1024 + 512 + krel);
#pragma unroll
        for (int mt = 0; mt < 4; ++mt) {
          accr[mt] = MFMA(a[mt], br, accr[mt]);
          accz[mt] = MFMA(a[mt], bz, accz[mt]);
          accxn[mt] = MFMA(a[mt], bn, accxn[mt]);
        }
      }

      if (p < 3) {
#pragma unroll
        for (int mt = 0; mt < 4; ++mt)
#pragma unroll
          for (int jp = 0; jp < 2; ++jp) {
            unsigned pk = 0;
#pragma unroll
            for (int jh = 0; jh < 2; ++jh) {
              const int j = jp * 2 + jh;
              const int row = mt * 16 + ks * 4 + j;
              float rr = sigm(accr[mt][j] + b_r[p]);
              float zz = sigm(accz[mt][j] + b_z[p]);
              float nn = tanh_(accxn[mt][j] + b_xn[p] +
                               rr * (acchn[mt][j] + b_hn[p]));
              float hold = bf2f(h_s[row * LROW + dcol]);
              float hnew = (t < len_s[row]) ? ((1.f - zz) * nn + zz * hold) : hold;
              pk |= ((unsigned)f2bf(hnew)) << (16 * jh);
            }
            holdp[p][mt][jp] = pk;
          }
      } else {
        __syncthreads();
#pragma unroll
        for (int pp = 0; pp < 3; ++pp) {
          const int dd = (pp * 8 + wave) * 16 + ln;
#pragma unroll
          for (int mt = 0; mt < 4; ++mt)
#pragma unroll
            for (int jp = 0; jp < 2; ++jp) {
              unsigned pk = holdp[pp][mt][jp];
              const int row = mt * 16 + ks * 4 + jp * 2;
              h_s[row * LROW + dd] = (u16)pk;
              h_s[(row + 1) * LROW + dd] = (u16)(pk >> 16);
            }
        }
#pragma unroll
        for (int mt = 0; mt < 4; ++mt)
#pragma unroll
          for (int j = 0; j < 4; ++j) {
            const int row = mt * 16 + ks * 4 + j;
            float rr = sigm(accr[mt][j] + b_r[3]);
            float zz = sigm(accz[mt][j] + b_z[3]);
            float nn = tanh_(accxn[mt][j] + b_xn[3] +
                             rr * (acchn[mt][j] + b_hn[3]));
            float hold = bf2f(h_s[row * LROW + dcol]);
            float hnew = (t < len_s[row]) ? ((1.f - zz) * nn + zz * hold) : hold;
            h_s[row * LROW + dcol] = f2bf(hnew);
          }
      }
    }
  }

  __syncthreads();
#pragma unroll
  for (int i = 0; i < 8; ++i) {
    int off = xcol * 8 + i * 64;
    u16x8 v = *(const u16x8*)(h_s + xrow * LROW + off);
    __builtin_nontemporal_store(
        v, (u16x8*)(hcat + (size_t)(s0 + xrow) * 1024 + dir * 512 + off));
  }
}

// ---------------------------------------------------------------------------
// MLP GEMM: out[M,N] = act(A[M,K] @ Bw[N,K]^T + bias)
// ---------------------------------------------------------------------------
__global__ __launch_bounds__(256) void mlp_gemm(const u16* __restrict__ A,
                                                const u16* __restrict__ Bw,
                                                const float* __restrict__ bias,
                                                void* __restrict__ out, int M,
                                                int N, int K, int mode) {
  __shared__ u16 As[128 * 64], Bs[128 * 64];
  const int tid = threadIdx.x;
  const int wave = tid >> 6, lane = tid & 63;
  const int ln = lane & 15, ks = lane >> 4;
  const int wm = wave & 1, wn = wave >> 1;
  const int m0 = blockIdx.x * 128, n0 = blockIdx.y * 128;
  f32x4 acc[4][4];
#pragma unroll
  for (int mt = 0; mt < 4; ++mt)
#pragma unroll
    for (int nt = 0; nt < 4; ++nt)
#pragma unroll
      for (int j = 0; j < 4; ++j) acc[mt][nt][j] = 0.f;

  const int r = tid >> 1, hh = tid & 1;
  for (int k0 = 0; k0 < K; k0 += 64) {
    const i32x4* sa = (const i32x4*)(A + (size_t)(m0 + r) * K + k0 + hh * 32);
    const i32x4* sb = (const i32x4*)(Bw + (size_t)(n0 + r) * K + k0 + hh * 32);
    i32x4* da = (i32x4*)(As + r * 64 + hh * 32);
    i32x4* db = (i32x4*)(Bs + r * 64 + hh * 32);
#pragma unroll
    for (int i = 0; i < 4; ++i) da[i] = sa[i];
#pragma unroll
    for (int i = 0; i < 4; ++i) db[i] = sb[i];
    __syncthreads();
#pragma unroll
    for (int kk = 0; kk < 2; ++kk) {
      bf16x8 af[4], bfm[4];
#pragma unroll
      for (int mt = 0; mt < 4; ++mt)
        af[mt] = *(const bf16x8*)(As + (wm * 64 + mt * 16 + ln) * 64 + kk * 32 + ks * 8);
#pragma unroll
      for (int nt = 0; nt < 4; ++nt)
        bfm[nt] = *(const bf16x8*)(Bs + (wn * 64 + nt * 16 + ln) * 64 + kk * 32 + ks * 8);
#pragma unroll
      for (int mt = 0; mt < 4; ++mt)
#pragma unroll
        for (int nt = 0; nt < 4; ++nt) acc[mt][nt] = MFMA(af[mt], bfm[nt], acc[mt][nt]);
    }
    __syncthreads();
  }

#pragma unroll
  for (int nt = 0; nt < 4; ++nt) {
    int col = n0 + wn * 64 + nt * 16 + ln;
    float bv = bias[col];
#pragma unroll
    for (int mt = 0; mt < 4; ++mt)
#pragma unroll
      for (int j = 0; j < 4; ++j) {
        int row = m0 + wm * 64 + mt * 16 + ks * 4 + j;
        float v = acc[mt][nt][j] + bv;
        if (mode) {
          v = fmaxf(v, 0.f);
          ((u16*)out)[(size_t)row * N + col] = f2bf(v);
        } else {
          ((float*)out)[(size_t)row * N + col] = v;
        }
      }
  }
}

// ---------------------------------------------------------------------------
extern "C" void kernel_launch(void* const* d_in, const int* in_sizes, int n_in,
                              void* d_out, int out_size, void* d_ws, size_t ws_size,
                              hipStream_t stream) {
  (void)in_sizes; (void)n_in; (void)out_size;
  const float* win = (const float*)d_in[0];
  const int* wlen = (const int*)d_in[1];
  const float* Wih_f = (const float*)d_in[2];
  const float* Whh_f = (const float*)d_in[3];
  const float* bih_f = (const float*)d_in[4];
  const float* bhh_f = (const float*)d_in[5];
  const float* Wih_b = (const float*)d_in[6];
  const float* Whh_b = (const float*)d_in[7];
  const float* bih_b = (const float*)d_in[8];
  const float* bhh_b = (const float*)d_in[9];
  const float* W1 = (const float*)d_in[10];
  const float* b1 = (const float*)d_in[11];
  const float* W2 = (const float*)d_in[12];
  const float* b2 = (const float*)d_in[13];

  // New-path workspace: 4x Wb(1.5MB) + W1b + W2b + hcat + hidden + xp(384MB)
  const size_t NEED = 4ull * 1572864 + 1048576 + 524288 + 16777216 + 8388608 +
                      402653184ull;  // = 435,683,328

  if (ws_size >= NEED) {
    char* ws = (char*)d_ws;
    u16* Whhb_f = (u16*)ws; ws += 1572864;
    u16* Whhb_b = (u16*)ws; ws += 1572864;
    u16* Wihb_f = (u16*)ws; ws += 1572864;
    u16* Wihb_b = (u16*)ws; ws += 1572864;
    u16* W1b = (u16*)ws;    ws += 1048576;
    u16* W2b = (u16*)ws;    ws += 524288;
    u16* hcat = (u16*)ws;   ws += 16777216;
    u16* hidden = (u16*)ws; ws += 8388608;
    u16* xp = (u16*)ws;     ws += 402653184;

    cvt_bf16<<<384, 256, 0, stream>>>(Whh_f, Whhb_f, 98304);
    cvt_bf16<<<384, 256, 0, stream>>>(Whh_b, Whhb_b, 98304);
    cvt_bf16<<<384, 256, 0, stream>>>(Wih_f, Wihb_f, 98304);
    cvt_bf16<<<384, 256, 0, stream>>>(Wih_b, Wihb_b, 98304);
    cvt_bf16<<<256, 256, 0, stream>>>(W1, W1b, 65536);
    cvt_bf16<<<128, 256, 0, stream>>>(W2, W2b, 32768);

    xp_gemm<<<dim3(512, 12), 256, 0, stream>>>(win, wlen, Wihb_f, bih_f, xp, 0);
    xp_gemm<<<dim3(512, 12), 256, 0, stream>>>(win, wlen, Wihb_b, bih_b, xp, 1);

    const int SMEM = 2 * 64 * LROW * 2 + 64 * 4 + 16;
    (void)hipFuncSetAttribute((const void*)gru_rec,
                              hipFuncAttributeMaxDynamicSharedMemorySize, SMEM);
    gru_rec<<<256, 512, SMEM, stream>>>(wlen, Whhb_f, Whhb_b, bhh_f, bhh_b, xp,
                                        hcat);

    mlp_gemm<<<dim3(64, 4), 256, 0, stream>>>(hcat, W1b, b1, hidden, 8192, 512, 1024, 1);
    mlp_gemm<<<dim3(64, 4), 256, 0, stream>>>(hidden, W2b, b2, d_out, 8192, 512, 512, 0);
  } else {
    // fallback: fused round-2 path (needs ~33 MB)
    char* ws = (char*)d_ws;
    u16* Wcat_f = (u16*)ws;  ws += 3145728;
    u16* Wcat_b = (u16*)ws;  ws += 3145728;
    u16* W1b = (u16*)ws;     ws += 1048576;
    u16* W2b = (u16*)ws;     ws += 524288;
    u16* hcat = (u16*)ws;    ws += 16777216;
    u16* hidden = (u16*)ws;  ws += 8388608;

    build_wcat<<<768, 256, 0, stream>>>(Whh_f, Wih_f, Wcat_f);
    build_wcat<<<768, 256, 0, stream>>>(Whh_b, Wih_b, Wcat_b);
    cvt_bf16<<<256, 256, 0, stream>>>(W1, W1b, 65536);
    cvt_bf16<<<128, 256, 0, stream>>>(W2, W2b, 32768);

    const int SMEM = 2 * 64 * LROW * 2 + 64 * 4 + 16;
    (void)hipFuncSetAttribute((const void*)gru_persistent,
                              hipFuncAttributeMaxDynamicSharedMemorySize, SMEM);
    gru_persistent<<<256, 512, SMEM, stream>>>(win, wlen, Wcat_f, Wcat_b, bih_f,
                                               bhh_f, bih_b, bhh_b, hcat);

    mlp_gemm<<<dim3(64, 4), 256, 0, stream>>>(hcat, W1b, b1, hidden, 8192, 512, 1024, 1);
    mlp_gemm<<<dim3(64, 4), 256, 0, stream>>>(hidden, W2b, b2, d_out, 8192, 512, 512, 0);
  }
}

// Round 5
// 2078.514 us; speedup vs baseline: 1.6551x; 1.6551x over previous
//
#include <hip/hip_runtime.h>

typedef unsigned short u16;
typedef __attribute__((ext_vector_type(4))) float f32x4;
typedef __attribute__((ext_vector_type(8))) __bf16 bf16x8;
typedef __attribute__((ext_vector_type(8))) u16 u16x8;
typedef __attribute__((ext_vector_type(4))) int i32x4;

#define MFMA(a, b, c) __builtin_amdgcn_mfma_f32_16x16x32_bf16(a, b, c, 0, 0, 0)

__device__ __forceinline__ u16 f2bf(float f) {
  union { float f; unsigned u; } v; v.f = f;
  unsigned r = v.u + 0x7FFFu + ((v.u >> 16) & 1u);
  return (u16)(r >> 16);
}
__device__ __forceinline__ float bf2f(u16 b) {
  union { unsigned u; float f; } v; v.u = ((unsigned)b) << 16; return v.f;
}
__device__ __forceinline__ float sigm(float x) { return 1.f / (1.f + __expf(-x)); }
__device__ __forceinline__ float tanh_(float x) {
  float e = __expf(-2.f * fabsf(x));
  float r = (1.f - e) / (1.f + e);
  return x < 0.f ? -r : r;
}

// xp layout: xp[((dir*8 + t)*96 + g)*131072 + s*16 + cw]
//   g = gate-column chunk (col>>4, 96 chunks of 16), s = sample, cw = col&15.
// GSTRIDE = 8192*16 = 131072 elements per (t,g) plane.
#define GSTRIDE 131072

// ---------------------------------------------------------------------------
// cvt_bf16: f32 -> bf16 (weights)
// ---------------------------------------------------------------------------
__global__ __launch_bounds__(256) void cvt_bf16(const float* __restrict__ src,
                                                u16* __restrict__ dst, int n8) {
  int i = blockIdx.x * 256 + threadIdx.x;
  if (i >= n8) return;
  int e = i * 8;
  u16x8 o;
#pragma unroll
  for (int j = 0; j < 8; ++j) o[j] = f2bf(src[e + j]);
  *(u16x8*)(dst + e) = o;
}

// ---------------------------------------------------------------------------
// xp_gemm v3: one block = 128 gathered rows x FULL N=1536. A staged once in
// LDS (133KB, 1 block/CU); B (Wih bf16, 1.5MB) read per-fragment from L2
// (re-read by every block but L2-resident). Grid (512, 2=dir). Plain cached
// loads (round-3's NT A-loads defeated L2 on the 12x n-tile reuse -> 3.2GB).
// Biases bih(+bhh for r,z) folded into xp here.
// ---------------------------------------------------------------------------
#define LROWA 520  // LDS A row stride (bf16 elems)

__global__ __launch_bounds__(256)
__attribute__((amdgpu_waves_per_eu(1, 1))) void xp_gemm(
    const float* __restrict__ win, const int* __restrict__ wlen,
    const u16* __restrict__ Wihb_f, const u16* __restrict__ Wihb_b,
    const float* __restrict__ bih_f, const float* __restrict__ bih_b,
    const float* __restrict__ bhh_f, const float* __restrict__ bhh_b,
    u16* __restrict__ xp) {
  extern __shared__ char smem[];
  u16* As = (u16*)smem;  // [128][LROWA]

  const int dir = blockIdx.y;
  const u16* Wb = dir ? Wihb_b : Wihb_f;
  const float* bih = dir ? bih_b : bih_f;
  const float* bhh = dir ? bhh_b : bhh_f;

  const int tid = threadIdx.x;
  const int bx = blockIdx.x;

  // ---- stage A: 128 gathered rows, f32 -> bf16 ----
  {
    const int r = tid >> 1, hh = tid & 1;
    const int m = bx * 128 + r;
    const int s = m >> 3, tt = m & 7;
    const int wl = wlen[s];
    const int len = dir ? (wl / 2 + 1) : ((wl - 1) / 2 + 1);
    const int widx = dir ? (6 + len - tt) : (8 - len + tt);
    const float* src = win + ((size_t)s * 15 + widx) * 512 + hh * 256;
    u16* dst = As + r * LROWA + hh * 256;
#pragma unroll
    for (int i = 0; i < 32; ++i) {
      f32x4 v0 = *(const f32x4*)(src + i * 8);
      f32x4 v1 = *(const f32x4*)(src + i * 8 + 4);
      u16x8 o;
      o[0] = f2bf(v0[0]); o[1] = f2bf(v0[1]); o[2] = f2bf(v0[2]); o[3] = f2bf(v0[3]);
      o[4] = f2bf(v1[0]); o[5] = f2bf(v1[1]); o[6] = f2bf(v1[2]); o[7] = f2bf(v1[3]);
      *(u16x8*)(dst + i * 8) = o;
    }
  }
  __syncthreads();

  const int wave = tid >> 6;
  const int lane = tid & 63;
  const int ln = lane & 15;
  const int ks = lane >> 4;

  // ---- each wave: 24 n-chunks in 6 groups of 4; full M=128 per group ----
#pragma unroll 1
  for (int g = 0; g < 6; ++g) {
    const int c0 = wave * 24 + g * 4;  // first chunk of this group

    f32x4 acc[8][4];
#pragma unroll
    for (int mt = 0; mt < 8; ++mt)
#pragma unroll
      for (int u = 0; u < 4; ++u)
#pragma unroll
        for (int j = 0; j < 4; ++j) acc[mt][u][j] = 0.f;

#pragma unroll
    for (int kk = 0; kk < 16; ++kk) {
      const int krel = kk * 32 + ks * 8;
      bf16x8 a[8];
#pragma unroll
      for (int mt = 0; mt < 8; ++mt)
        a[mt] = *(const bf16x8*)(As + (mt * 16 + ln) * LROWA + krel);
      bf16x8 b[4];
#pragma unroll
      for (int u = 0; u < 4; ++u)
        b[u] = *(const bf16x8*)(Wb + (size_t)((c0 + u) * 16 + ln) * 512 + krel);
#pragma unroll
      for (int mt = 0; mt < 8; ++mt)
#pragma unroll
        for (int u = 0; u < 4; ++u) acc[mt][u] = MFMA(a[mt], b[u], acc[mt][u]);
    }

    // epilogue: fold biases, store to gru-friendly xp layout
#pragma unroll
    for (int u = 0; u < 4; ++u) {
      const int col = (c0 + u) * 16 + ln;
      const float bv = bih[col] + (col < 1024 ? bhh[col] : 0.f);
#pragma unroll
      for (int mt = 0; mt < 8; ++mt)
#pragma unroll
        for (int j = 0; j < 4; ++j) {
          const int rowm = bx * 128 + mt * 16 + ks * 4 + j;
          const int s = rowm >> 3, t = rowm & 7;
          const size_t idx =
              ((size_t)(dir * 8 + t) * 96 + (c0 + u)) * GSTRIDE + (size_t)s * 16 + ln;
          xp[idx] = f2bf(acc[mt][u][j] + bv);
        }
    }
  }
}

// ---------------------------------------------------------------------------
// gru_rec: recurrent h-half only. 256 blocks x 512 threads (8 waves).
// Per step t: gh = h(64x512) @ Whh^T(512x1536); 4 N-quarter passes x 8 waves.
// xp (precomputed, biases folded) read with PLAIN cached loads in the
// [t][g][s][16] layout: each wave load = 4x32B segments, full line reuse
// across the j-loop (round-3's NT scatter caused 4.5x HBM overfetch).
// h double-buffered in LDS; ONE barrier per step. Whh 1.5MB/dir (L2-fit).
// ---------------------------------------------------------------------------
#define LROW 520  // padded LDS row stride (bf16) to break bank conflicts

__global__ __launch_bounds__(512)
__attribute__((amdgpu_waves_per_eu(2, 2))) void gru_rec(
    const int* __restrict__ wlen, const u16* __restrict__ Whhb_f,
    const u16* __restrict__ Whhb_b, const float* __restrict__ bhh_f,
    const float* __restrict__ bhh_b, const u16* __restrict__ xp,
    u16* __restrict__ hcat) {
  extern __shared__ char smem[];
  u16* hb0 = (u16*)smem;       // [64][LROW]
  u16* hb1 = hb0 + 64 * LROW;  // [64][LROW]
  int* len_s = (int*)(hb1 + 64 * LROW);
  int* bmax_s = len_s + 64;

  const int dir = blockIdx.x & 1;
  const int grp = blockIdx.x >> 1;
  const int s0 = grp * 64;
  const u16* W = dir ? Whhb_b : Whhb_f;
  const float* bhh = dir ? bhh_b : bhh_f;

  const int tid = threadIdx.x;
  const int wave = tid >> 6;
  const int lane = tid & 63;
  const int ln = lane & 15;
  const int ks = lane >> 4;  // 0..3

  // ---- init: zero hb0, lengths + block max ----
  if (tid == 0) *bmax_s = 0;
  for (int i = tid; i < 64 * LROW / 8; i += 512) ((u16x8*)hb0)[i] = (u16x8)0;
  __syncthreads();
  if (tid < 64) {
    int wl = wlen[s0 + tid];
    int len = dir ? (wl / 2 + 1) : ((wl - 1) / 2 + 1);
    len_s[tid] = len;
    atomicMax(bmax_s, len);
  }
  __syncthreads();
  const int bmax = *bmax_s;

  // only the n-gate recurrent bias survives (r,z biases folded into xp)
  float b_hn[4];
#pragma unroll
  for (int p = 0; p < 4; ++p) b_hn[p] = bhh[1024 + (p * 8 + wave) * 16 + ln];

  for (int t = 0; t < bmax; ++t) {
    u16* h_cur = (t & 1) ? hb1 : hb0;
    u16* h_nxt = (t & 1) ? hb0 : hb1;
    const u16* xpt = xp + (size_t)(dir * 8 + t) * 96 * GSTRIDE;

#pragma unroll
    for (int p = 0; p < 4; ++p) {
      const int dcol = (p * 8 + wave) * 16 + ln;
      const u16* wrow = W + (size_t)dcol * 512;
      const u16* xg = xpt + (size_t)(p * 8 + wave) * GSTRIDE + ln;

      f32x4 accr[4], accz[4], acchn[4];
#pragma unroll
      for (int mt = 0; mt < 4; ++mt)
#pragma unroll
        for (int j = 0; j < 4; ++j) {
          accr[mt][j] = 0.f; accz[mt][j] = 0.f; acchn[mt][j] = 0.f;
        }

#pragma unroll
      for (int kk = 0; kk < 16; ++kk) {
        const int krel = kk * 32 + ks * 8;
        bf16x8 a[4];
#pragma unroll
        for (int mt = 0; mt < 4; ++mt)
          a[mt] = *(const bf16x8*)(h_cur + (mt * 16 + ln) * LROW + krel);
        bf16x8 br = *(const bf16x8*)(wrow + krel);
        bf16x8 bz = *(const bf16x8*)(wrow + 512 * 512 + krel);
        bf16x8 bn = *(const bf16x8*)(wrow + 1024 * 512 + krel);
#pragma unroll
        for (int mt = 0; mt < 4; ++mt) {
          accr[mt] = MFMA(a[mt], br, accr[mt]);
          accz[mt] = MFMA(a[mt], bz, accz[mt]);
          acchn[mt] = MFMA(a[mt], bn, acchn[mt]);
        }
      }

      // epilogue: cached xp loads (r/z/n planes 32*GSTRIDE apart)
#pragma unroll
      for (int mt = 0; mt < 4; ++mt)
#pragma unroll
        for (int j = 0; j < 4; ++j) {
          const int row = mt * 16 + ks * 4 + j;
          const u16* xq = xg + (size_t)(s0 + row) * 16;
          float xr = bf2f(xq[0]);
          float xz = bf2f(xq[32 * GSTRIDE]);
          float xn = bf2f(xq[64 * GSTRIDE]);
          float rr = sigm(accr[mt][j] + xr);
          float zz = sigm(accz[mt][j] + xz);
          float nn = tanh_(xn + rr * (acchn[mt][j] + b_hn[p]));
          float hold = bf2f(h_cur[row * LROW + dcol]);
          float hnew = (t < len_s[row]) ? ((1.f - zz) * nn + zz * hold) : hold;
          h_nxt[row * LROW + dcol] = f2bf(hnew);
        }
    }  // passes
    __syncthreads();  // h_nxt complete before it becomes h_cur
  }    // t

  // ---- write final h to hcat[s][dir*512 + k] ----
  const u16* hf = (bmax & 1) ? hb1 : hb0;
  const int xrow = tid >> 3;
  const int xcol = tid & 7;
#pragma unroll
  for (int i = 0; i < 8; ++i) {
    int off = xcol * 8 + i * 64;
    u16x8 v = *(const u16x8*)(hf + xrow * LROW + off);
    __builtin_nontemporal_store(
        v, (u16x8*)(hcat + (size_t)(s0 + xrow) * 1024 + dir * 512 + off));
  }
}

// ---------------------------------------------------------------------------
// FALLBACK path (ws too small): round-2 fused kernel.
// ---------------------------------------------------------------------------
__global__ __launch_bounds__(256) void build_wcat(const float* __restrict__ Whh,
                                                  const float* __restrict__ Wih,
                                                  u16* __restrict__ Wcat) {
  int i = blockIdx.x * 256 + threadIdx.x;
  if (i >= 1536 * 1024 / 8) return;
  int e = i * 8;
  int g = e >> 10, k = e & 1023;
  const float* src = (k < 512) ? (Whh + g * 512 + k) : (Wih + g * 512 + (k - 512));
  u16x8 o;
#pragma unroll
  for (int j = 0; j < 8; ++j) o[j] = f2bf(src[j]);
  *(u16x8*)(Wcat + e) = o;
}

__global__ __launch_bounds__(512)
__attribute__((amdgpu_waves_per_eu(2, 2))) void gru_persistent(
    const float* __restrict__ win, const int* __restrict__ wlen,
    const u16* __restrict__ Wcat_f, const u16* __restrict__ Wcat_b,
    const float* __restrict__ bih_f, const float* __restrict__ bhh_f,
    const float* __restrict__ bih_b, const float* __restrict__ bhh_b,
    u16* __restrict__ hcat) {
  extern __shared__ char smem[];
  u16* h_s = (u16*)smem;
  u16* x_s = (u16*)(smem + 64 * LROW * 2);
  int* len_s = (int*)(smem + 2 * 64 * LROW * 2);
  int* bmax_s = len_s + 64;

  const int dir = blockIdx.x & 1;
  const int grp = blockIdx.x >> 1;
  const int s0 = grp * 64;
  const u16* W = dir ? Wcat_b : Wcat_f;
  const float* bih = dir ? bih_b : bih_f;
  const float* bhh = dir ? bhh_b : bhh_f;

  const int tid = threadIdx.x;
  const int wave = tid >> 6;
  const int lane = tid & 63;
  const int ln = lane & 15;
  const int ks = lane >> 4;

  if (tid == 0) *bmax_s = 0;
  for (int i = tid; i < 64 * LROW / 8; i += 512) ((u16x8*)h_s)[i] = (u16x8)0;
  __syncthreads();
  if (tid < 64) {
    int wl = wlen[s0 + tid];
    int len = dir ? (wl / 2 + 1) : ((wl - 1) / 2 + 1);
    len_s[tid] = len;
    atomicMax(bmax_s, len);
  }
  __syncthreads();
  const int bmax = *bmax_s;

  float b_r[4], b_z[4], b_xn[4], b_hn[4];
#pragma unroll
  for (int p = 0; p < 4; ++p) {
    int d = (p * 8 + wave) * 16 + ln;
    b_r[p] = bih[d] + bhh[d];
    b_z[p] = bih[512 + d] + bhh[512 + d];
    b_xn[p] = bih[1024 + d];
    b_hn[p] = bhh[1024 + d];
  }

  const int xrow = tid >> 3;
  const int xcol = tid & 7;
  const int mylen = len_s[xrow];
  const long xbase = (long)(s0 + xrow) * 15 + (dir ? (6 + mylen) : (8 - mylen));

  for (int t = 0; t < bmax; ++t) {
    {
      long rowidx = dir ? (xbase - t) : (xbase + t);
      const float* src = win + rowidx * 512;
      u16* dst = x_s + xrow * LROW;
#pragma unroll
      for (int i = 0; i < 8; ++i) {
        int off = xcol * 8 + i * 64;
        f32x4 v0 = *(const f32x4*)(src + off);
        f32x4 v1 = *(const f32x4*)(src + off + 4);
        u16x8 o;
        o[0] = f2bf(v0[0]); o[1] = f2bf(v0[1]); o[2] = f2bf(v0[2]); o[3] = f2bf(v0[3]);
        o[4] = f2bf(v1[0]); o[5] = f2bf(v1[1]); o[6] = f2bf(v1[2]); o[7] = f2bf(v1[3]);
        *(u16x8*)(dst + off) = o;
      }
    }
    __syncthreads();

    unsigned holdp[3][4][2];

#pragma unroll
    for (int p = 0; p < 4; ++p) {
      const int dcol = (p * 8 + wave) * 16 + ln;
      const u16* wrow = W + (size_t)dcol * 1024;

      f32x4 accr[4], accz[4], acchn[4], accxn[4];
#pragma unroll
      for (int mt = 0; mt < 4; ++mt)
#pragma unroll
        for (int j = 0; j < 4; ++j) {
          accr[mt][j] = 0.f; accz[mt][j] = 0.f;
          acchn[mt][j] = 0.f; accxn[mt][j] = 0.f;
        }

#pragma unroll
      for (int kk = 0; kk < 16; ++kk) {
        const int krel = kk * 32 + ks * 8;
        bf16x8 a[4];
#pragma unroll
        for (int mt = 0; mt < 4; ++mt)
          a[mt] = *(const bf16x8*)(h_s + (mt * 16 + ln) * LROW + krel);
        bf16x8 br = *(const bf16x8*)(wrow + krel);
        bf16x8 bz = *(const bf16x8*)(wrow + 512 * 1024 + krel);
        bf16x8 bn = *(const bf16x8*)(wrow + 1024 * 1024 + krel);
#pragma unroll
        for (int mt = 0; mt < 4; ++mt) {
          accr[mt] = MFMA(a[mt], br, accr[mt]);
          accz[mt] = MFMA(a[mt], bz, accz[mt]);
          acchn[mt] = MFMA(a[mt], bn, acchn[mt]);
        }
      }
#pragma unroll
      for (int kk = 0; kk < 16; ++kk) {
        const int krel = kk * 32 + ks * 8;
        bf16x8 a[4];
#pragma unroll
        for (int mt = 0; mt < 4; ++mt)
          a[mt] = *(const bf16x8*)(x_s + (mt * 16 + ln) * LROW + krel);
        bf16x8 br = *(const bf16x8*)(wrow + 512 + krel);
        bf16x8 bz = *(const bf16x8*)(wrow + 512 * 1024 + 512 + krel);
        bf16x8 bn = *(const bf16x8*)(wrow + 1024 * 1024 + 512 + krel);
#pragma unroll
        for (int mt = 0; mt < 4; ++mt) {
          accr[mt] = MFMA(a[mt], br, accr[mt]);
          accz[mt] = MFMA(a[mt], bz, accz[mt]);
          accxn[mt] = MFMA(a[mt], bn, accxn[mt]);
        }
      }

      if (p < 3) {
#pragma unroll
        for (int mt = 0; mt < 4; ++mt)
#pragma unroll
          for (int jp = 0; jp < 2; ++jp) {
            unsigned pk = 0;
#pragma unroll
            for (int jh = 0; jh < 2; ++jh) {
              const int j = jp * 2 + jh;
              const int row = mt * 16 + ks * 4 + j;
              float rr = sigm(accr[mt][j] + b_r[p]);
              float zz = sigm(accz[mt][j] + b_z[p]);
              float nn = tanh_(accxn[mt][j] + b_xn[p] +
                               rr * (acchn[mt][j] + b_hn[p]));
              float hold = bf2f(h_s[row * LROW + dcol]);
              float hnew = (t < len_s[row]) ? ((1.f - zz) * nn + zz * hold) : hold;
              pk |= ((unsigned)f2bf(hnew)) << (16 * jh);
            }
            holdp[p][mt][jp] = pk;
          }
      } else {
        __syncthreads();
#pragma unroll
        for (int pp = 0; pp < 3; ++pp) {
          const int dd = (pp * 8 + wave) * 16 + ln;
#pragma unroll
          for (int mt = 0; mt < 4; ++mt)
#pragma unroll
            for (int jp = 0; jp < 2; ++jp) {
              unsigned pk = holdp[pp][mt][jp];
              const int row = mt * 16 + ks * 4 + jp * 2;
              h_s[row * LROW + dd] = (u16)pk;
              h_s[(row + 1) * LROW + dd] = (u16)(pk >> 16);
            }
        }
#pragma unroll
        for (int mt = 0; mt < 4; ++mt)
#pragma unroll
          for (int j = 0; j < 4; ++j) {
            const int row = mt * 16 + ks * 4 + j;
            float rr = sigm(accr[mt][j] + b_r[3]);
            float zz = sigm(accz[mt][j] + b_z[3]);
            float nn = tanh_(accxn[mt][j] + b_xn[3] +
                             rr * (acchn[mt][j] + b_hn[3]));
            float hold = bf2f(h_s[row * LROW + dcol]);
            float hnew = (t < len_s[row]) ? ((1.f - zz) * nn + zz * hold) : hold;
            h_s[row * LROW + dcol] = f2bf(hnew);
          }
      }
    }
  }

  __syncthreads();
#pragma unroll
  for (int i = 0; i < 8; ++i) {
    int off = xcol * 8 + i * 64;
    u16x8 v = *(const u16x8*)(h_s + xrow * LROW + off);
    __builtin_nontemporal_store(
        v, (u16x8*)(hcat + (size_t)(s0 + xrow) * 1024 + dir * 512 + off));
  }
}

// ---------------------------------------------------------------------------
// MLP GEMM: out[M,N] = act(A[M,K] @ Bw[N,K]^T + bias)
// ---------------------------------------------------------------------------
__global__ __launch_bounds__(256) void mlp_gemm(const u16* __restrict__ A,
                                                const u16* __restrict__ Bw,
                                                const float* __restrict__ bias,
                                                void* __restrict__ out, int M,
                                                int N, int K, int mode) {
  __shared__ u16 As[128 * 64], Bs[128 * 64];
  const int tid = threadIdx.x;
  const int wave = tid >> 6, lane = tid & 63;
  const int ln = lane & 15, ks = lane >> 4;
  const int wm = wave & 1, wn = wave >> 1;
  const int m0 = blockIdx.x * 128, n0 = blockIdx.y * 128;
  f32x4 acc[4][4];
#pragma unroll
  for (int mt = 0; mt < 4; ++mt)
#pragma unroll
    for (int nt = 0; nt < 4; ++nt)
#pragma unroll
      for (int j = 0; j < 4; ++j) acc[mt][nt][j] = 0.f;

  const int r = tid >> 1, hh = tid & 1;
  for (int k0 = 0; k0 < K; k0 += 64) {
    const i32x4* sa = (const i32x4*)(A + (size_t)(m0 + r) * K + k0 + hh * 32);
    const i32x4* sb = (const i32x4*)(Bw + (size_t)(n0 + r) * K + k0 + hh * 32);
    i32x4* da = (i32x4*)(As + r * 64 + hh * 32);
    i32x4* db = (i32x4*)(Bs + r * 64 + hh * 32);
#pragma unroll
    for (int i = 0; i < 4; ++i) da[i] = sa[i];
#pragma unroll
    for (int i = 0; i < 4; ++i) db[i] = sb[i];
    __syncthreads();
#pragma unroll
    for (int kk = 0; kk < 2; ++kk) {
      bf16x8 af[4], bfm[4];
#pragma unroll
      for (int mt = 0; mt < 4; ++mt)
        af[mt] = *(const bf16x8*)(As + (wm * 64 + mt * 16 + ln) * 64 + kk * 32 + ks * 8);
#pragma unroll
      for (int nt = 0; nt < 4; ++nt)
        bfm[nt] = *(const bf16x8*)(Bs + (wn * 64 + nt * 16 + ln) * 64 + kk * 32 + ks * 8);
#pragma unroll
      for (int mt = 0; mt < 4; ++mt)
#pragma unroll
        for (int nt = 0; nt < 4; ++nt) acc[mt][nt] = MFMA(af[mt], bfm[nt], acc[mt][nt]);
    }
    __syncthreads();
  }

#pragma unroll
  for (int nt = 0; nt < 4; ++nt) {
    int col = n0 + wn * 64 + nt * 16 + ln;
    float bv = bias[col];
#pragma unroll
    for (int mt = 0; mt < 4; ++mt)
#pragma unroll
      for (int j = 0; j < 4; ++j) {
        int row = m0 + wm * 64 + mt * 16 + ks * 4 + j;
        float v = acc[mt][nt][j] + bv;
        if (mode) {
          v = fmaxf(v, 0.f);
          ((u16*)out)[(size_t)row * N + col] = f2bf(v);
        } else {
          ((float*)out)[(size_t)row * N + col] = v;
        }
      }
  }
}

// ---------------------------------------------------------------------------
extern "C" void kernel_launch(void* const* d_in, const int* in_sizes, int n_in,
                              void* d_out, int out_size, void* d_ws, size_t ws_size,
                              hipStream_t stream) {
  (void)in_sizes; (void)n_in; (void)out_size;
  const float* win = (const float*)d_in[0];
  const int* wlen = (const int*)d_in[1];
  const float* Wih_f = (const float*)d_in[2];
  const float* Whh_f = (const float*)d_in[3];
  const float* bih_f = (const float*)d_in[4];
  const float* bhh_f = (const float*)d_in[5];
  const float* Wih_b = (const float*)d_in[6];
  const float* Whh_b = (const float*)d_in[7];
  const float* bih_b = (const float*)d_in[8];
  const float* bhh_b = (const float*)d_in[9];
  const float* W1 = (const float*)d_in[10];
  const float* b1 = (const float*)d_in[11];
  const float* W2 = (const float*)d_in[12];
  const float* b2 = (const float*)d_in[13];

  const size_t NEED = 4ull * 1572864 + 1048576 + 524288 + 16777216 + 8388608 +
                      402653184ull;  // = 435,683,328

  if (ws_size >= NEED) {
    char* ws = (char*)d_ws;
    u16* Whhb_f = (u16*)ws; ws += 1572864;
    u16* Whhb_b = (u16*)ws; ws += 1572864;
    u16* Wihb_f = (u16*)ws; ws += 1572864;
    u16* Wihb_b = (u16*)ws; ws += 1572864;
    u16* W1b = (u16*)ws;    ws += 1048576;
    u16* W2b = (u16*)ws;    ws += 524288;
    u16* hcat = (u16*)ws;   ws += 16777216;
    u16* hidden = (u16*)ws; ws += 8388608;
    u16* xp = (u16*)ws;     ws += 402653184;

    cvt_bf16<<<384, 256, 0, stream>>>(Whh_f, Whhb_f, 98304);
    cvt_bf16<<<384, 256, 0, stream>>>(Whh_b, Whhb_b, 98304);
    cvt_bf16<<<384, 256, 0, stream>>>(Wih_f, Wihb_f, 98304);
    cvt_bf16<<<384, 256, 0, stream>>>(Wih_b, Wihb_b, 98304);
    cvt_bf16<<<256, 256, 0, stream>>>(W1, W1b, 65536);
    cvt_bf16<<<128, 256, 0, stream>>>(W2, W2b, 32768);

    const int SMEM_XP = 128 * LROWA * 2;  // 133,120 B
    (void)hipFuncSetAttribute((const void*)xp_gemm,
                              hipFuncAttributeMaxDynamicSharedMemorySize, SMEM_XP);
    xp_gemm<<<dim3(512, 2), 256, SMEM_XP, stream>>>(
        win, wlen, Wihb_f, Wihb_b, bih_f, bih_b, bhh_f, bhh_b, xp);

    const int SMEM = 2 * 64 * LROW * 2 + 64 * 4 + 16;
    (void)hipFuncSetAttribute((const void*)gru_rec,
                              hipFuncAttributeMaxDynamicSharedMemorySize, SMEM);
    gru_rec<<<256, 512, SMEM, stream>>>(wlen, Whhb_f, Whhb_b, bhh_f, bhh_b, xp,
                                        hcat);

    mlp_gemm<<<dim3(64, 4), 256, 0, stream>>>(hcat, W1b, b1, hidden, 8192, 512, 1024, 1);
    mlp_gemm<<<dim3(64, 4), 256, 0, stream>>>(hidden, W2b, b2, d_out, 8192, 512, 512, 0);
  } else {
    char* ws = (char*)d_ws;
    u16* Wcat_f = (u16*)ws;  ws += 3145728;
    u16* Wcat_b = (u16*)ws;  ws += 3145728;
    u16* W1b = (u16*)ws;     ws += 1048576;
    u16* W2b = (u16*)ws;     ws += 524288;
    u16* hcat = (u16*)ws;    ws += 16777216;
    u16* hidden = (u16*)ws;  ws += 8388608;

    build_wcat<<<768, 256, 0, stream>>>(Whh_f, Wih_f, Wcat_f);
    build_wcat<<<768, 256, 0, stream>>>(Whh_b, Wih_b, Wcat_b);
    cvt_bf16<<<256, 256, 0, stream>>>(W1, W1b, 65536);
    cvt_bf16<<<128, 256, 0, stream>>>(W2, W2b, 32768);

    const int SMEM = 2 * 64 * LROW * 2 + 64 * 4 + 16;
    (void)hipFuncSetAttribute((const void*)gru_persistent,
                              hipFuncAttributeMaxDynamicSharedMemorySize, SMEM);
    gru_persistent<<<256, 512, SMEM, stream>>>(win, wlen, Wcat_f, Wcat_b, bih_f,
                                               bhh_f, bih_b, bhh_b, hcat);

    mlp_gemm<<<dim3(64, 4), 256, 0, stream>>>(hcat, W1b, b1, hidden, 8192, 512, 1024, 1);
    mlp_gemm<<<dim3(64, 4), 256, 0, stream>>>(hidden, W2b, b2, d_out, 8192, 512, 512, 0);
  }
}

// Round 6
// 1885.004 us; speedup vs baseline: 1.8250x; 1.1027x over previous
//
#include <hip/hip_runtime.h>

typedef unsigned short u16;
typedef __attribute__((ext_vector_type(4))) float f32x4;
typedef __attribute__((ext_vector_type(8))) __bf16 bf16x8;
typedef __attribute__((ext_vector_type(8))) u16 u16x8;
typedef __attribute__((ext_vector_type(4))) u16 u16x4;
typedef __attribute__((ext_vector_type(4))) int i32x4;

#define MFMA(a, b, c) __builtin_amdgcn_mfma_f32_16x16x32_bf16(a, b, c, 0, 0, 0)

__device__ __forceinline__ u16 f2bf(float f) {
  union { float f; unsigned u; } v; v.f = f;
  unsigned r = v.u + 0x7FFFu + ((v.u >> 16) & 1u);
  return (u16)(r >> 16);
}
__device__ __forceinline__ float bf2f(u16 b) {
  union { unsigned u; float f; } v; v.u = ((unsigned)b) << 16; return v.f;
}
__device__ __forceinline__ float sigm(float x) { return 1.f / (1.f + __expf(-x)); }
__device__ __forceinline__ float tanh_(float x) {
  float e = __expf(-2.f * fabsf(x));
  float r = (1.f - e) / (1.f + e);
  return x < 0.f ? -r : r;
}

// xp layout: plane = (dir*8 + t)*96 + g   (g = col>>4, 96 chunks of 16 cols)
// within plane: [s>>2][col&15][s&3]  -> offset = (s>>2)*64 + (col&15)*4 + (s&3)
// GSTRIDE = 8192*16 = 131072 elements per plane.
// This makes gru_rec's per-lane j-loop (4 consecutive samples) ONE u16x4 load.
#define GSTRIDE 131072

// ---------------------------------------------------------------------------
__global__ __launch_bounds__(256) void cvt_bf16(const float* __restrict__ src,
                                                u16* __restrict__ dst, int n8) {
  int i = blockIdx.x * 256 + threadIdx.x;
  if (i >= n8) return;
  int e = i * 8;
  u16x8 o;
#pragma unroll
  for (int j = 0; j < 8; ++j) o[j] = f2bf(src[e + j]);
  *(u16x8*)(dst + e) = o;
}

// ---------------------------------------------------------------------------
// xp_gemm: one block = 128 gathered rows x FULL N=1536. A staged once in LDS;
// B (Wih bf16, 1.5MB) read per-fragment from L2. Grid (512, 2=dir).
// Biases bih (+bhh for r,z) folded into xp here.
// ---------------------------------------------------------------------------
#define LROWA 520  // LDS A row stride (bf16 elems)

__global__ __launch_bounds__(256)
__attribute__((amdgpu_waves_per_eu(1, 1))) void xp_gemm(
    const float* __restrict__ win, const int* __restrict__ wlen,
    const u16* __restrict__ Wihb_f, const u16* __restrict__ Wihb_b,
    const float* __restrict__ bih_f, const float* __restrict__ bih_b,
    const float* __restrict__ bhh_f, const float* __restrict__ bhh_b,
    u16* __restrict__ xp) {
  extern __shared__ char smem[];
  u16* As = (u16*)smem;  // [128][LROWA]

  const int dir = blockIdx.y;
  const u16* Wb = dir ? Wihb_b : Wihb_f;
  const float* bih = dir ? bih_b : bih_f;
  const float* bhh = dir ? bhh_b : bhh_f;

  const int tid = threadIdx.x;
  const int bx = blockIdx.x;

  // ---- stage A: 128 gathered rows, f32 -> bf16 ----
  {
    const int r = tid >> 1, hh = tid & 1;
    const int m = bx * 128 + r;
    const int s = m >> 3, tt = m & 7;
    const int wl = wlen[s];
    const int len = dir ? (wl / 2 + 1) : ((wl - 1) / 2 + 1);
    const int widx = dir ? (6 + len - tt) : (8 - len + tt);
    const float* src = win + ((size_t)s * 15 + widx) * 512 + hh * 256;
    u16* dst = As + r * LROWA + hh * 256;
#pragma unroll
    for (int i = 0; i < 32; ++i) {
      f32x4 v0 = *(const f32x4*)(src + i * 8);
      f32x4 v1 = *(const f32x4*)(src + i * 8 + 4);
      u16x8 o;
      o[0] = f2bf(v0[0]); o[1] = f2bf(v0[1]); o[2] = f2bf(v0[2]); o[3] = f2bf(v0[3]);
      o[4] = f2bf(v1[0]); o[5] = f2bf(v1[1]); o[6] = f2bf(v1[2]); o[7] = f2bf(v1[3]);
      *(u16x8*)(dst + i * 8) = o;
    }
  }
  __syncthreads();

  const int wave = tid >> 6;
  const int lane = tid & 63;
  const int ln = lane & 15;
  const int ks = lane >> 4;

#pragma unroll 1
  for (int g = 0; g < 6; ++g) {
    const int c0 = wave * 24 + g * 4;

    f32x4 acc[8][4];
#pragma unroll
    for (int mt = 0; mt < 8; ++mt)
#pragma unroll
      for (int u = 0; u < 4; ++u)
#pragma unroll
        for (int j = 0; j < 4; ++j) acc[mt][u][j] = 0.f;

#pragma unroll
    for (int kk = 0; kk < 16; ++kk) {
      const int krel = kk * 32 + ks * 8;
      bf16x8 a[8];
#pragma unroll
      for (int mt = 0; mt < 8; ++mt)
        a[mt] = *(const bf16x8*)(As + (mt * 16 + ln) * LROWA + krel);
      bf16x8 b[4];
#pragma unroll
      for (int u = 0; u < 4; ++u)
        b[u] = *(const bf16x8*)(Wb + (size_t)((c0 + u) * 16 + ln) * 512 + krel);
#pragma unroll
      for (int mt = 0; mt < 8; ++mt)
#pragma unroll
        for (int u = 0; u < 4; ++u) acc[mt][u] = MFMA(a[mt], b[u], acc[mt][u]);
    }

    // epilogue: fold biases, store to gru-friendly xp layout
#pragma unroll
    for (int u = 0; u < 4; ++u) {
      const int col = (c0 + u) * 16 + ln;
      const float bv = bih[col] + (col < 1024 ? bhh[col] : 0.f);
#pragma unroll
      for (int mt = 0; mt < 8; ++mt)
#pragma unroll
        for (int j = 0; j < 4; ++j) {
          const int rowm = bx * 128 + mt * 16 + ks * 4 + j;
          const int s = rowm >> 3, t = rowm & 7;
          const size_t idx = ((size_t)(dir * 8 + t) * 96 + (c0 + u)) * GSTRIDE +
                             (size_t)(s >> 2) * 64 + ln * 4 + (s & 3);
          xp[idx] = f2bf(acc[mt][u][j] + bv);
        }
    }
  }
}

// ---------------------------------------------------------------------------
// gru_rec v3: 256 blocks x 1024 threads (16 waves -> 4 waves/SIMD, 2x the
// latency hiding of v2). Per step: 2 N-half passes x 16 waves x 16 cols.
// xp prefetched BEFORE the K-loop as 12 vectorized u16x4 loads/pass (was 48
// serial scalar cold-HBM loads in the epilogue -> the v2 latency chain).
// h double-buffered in LDS (133KB, 1 block/CU); ONE barrier per step.
// ---------------------------------------------------------------------------
#define LROW 520  // padded LDS row stride (bf16) to break bank conflicts

__global__ __launch_bounds__(1024)
__attribute__((amdgpu_waves_per_eu(4, 4))) void gru_rec(
    const int* __restrict__ wlen, const u16* __restrict__ Whhb_f,
    const u16* __restrict__ Whhb_b, const float* __restrict__ bhh_f,
    const float* __restrict__ bhh_b, const u16* __restrict__ xp,
    u16* __restrict__ hcat) {
  extern __shared__ char smem[];
  u16* hb0 = (u16*)smem;       // [64][LROW]
  u16* hb1 = hb0 + 64 * LROW;  // [64][LROW]
  int* len_s = (int*)(hb1 + 64 * LROW);
  int* bmax_s = len_s + 64;

  const int dir = blockIdx.x & 1;
  const int grp = blockIdx.x >> 1;
  const int s0 = grp * 64;
  const u16* W = dir ? Whhb_b : Whhb_f;
  const float* bhh = dir ? bhh_b : bhh_f;

  const int tid = threadIdx.x;
  const int wave = tid >> 6;  // 0..15
  const int lane = tid & 63;
  const int ln = lane & 15;
  const int ks = lane >> 4;  // 0..3

  // ---- init: zero hb0, lengths + block max ----
  if (tid == 0) *bmax_s = 0;
  for (int i = tid; i < 64 * LROW / 8; i += 1024) ((u16x8*)hb0)[i] = (u16x8)0;
  __syncthreads();
  if (tid < 64) {
    int wl = wlen[s0 + tid];
    int len = dir ? (wl / 2 + 1) : ((wl - 1) / 2 + 1);
    len_s[tid] = len;
    atomicMax(bmax_s, len);
  }
  __syncthreads();
  const int bmax = *bmax_s;

  // only the n-gate recurrent bias survives (r,z biases folded into xp)
  float b_hn[2];
#pragma unroll
  for (int p = 0; p < 2; ++p) b_hn[p] = bhh[1024 + (p * 16 + wave) * 16 + ln];

  for (int t = 0; t < bmax; ++t) {
    u16* h_cur = (t & 1) ? hb1 : hb0;
    u16* h_nxt = (t & 1) ? hb0 : hb1;
    const u16* xpt = xp + (size_t)(dir * 8 + t) * 96 * GSTRIDE;

#pragma unroll
    for (int p = 0; p < 2; ++p) {
      const int q = p * 16 + wave;       // gate-col chunk 0..31
      const int dcol = q * 16 + ln;
      const u16* wrow = W + (size_t)dcol * 512;

      // ---- prefetch xp for this pass: 12 vector loads, hidden by K-loop ----
      u16x4 xr4[4], xz4[4], xn4[4];
#pragma unroll
      for (int mt = 0; mt < 4; ++mt) {
        const size_t off = (size_t)((s0 >> 2) + mt * 4 + ks) * 64 + ln * 4;
        xr4[mt] = *(const u16x4*)(xpt + (size_t)q * GSTRIDE + off);
        xz4[mt] = *(const u16x4*)(xpt + (size_t)(32 + q) * GSTRIDE + off);
        xn4[mt] = *(const u16x4*)(xpt + (size_t)(64 + q) * GSTRIDE + off);
      }

      f32x4 accr[4], accz[4], acchn[4];
#pragma unroll
      for (int mt = 0; mt < 4; ++mt)
#pragma unroll
        for (int j = 0; j < 4; ++j) {
          accr[mt][j] = 0.f; accz[mt][j] = 0.f; acchn[mt][j] = 0.f;
        }

#pragma unroll
      for (int kk = 0; kk < 16; ++kk) {
        const int krel = kk * 32 + ks * 8;
        bf16x8 a[4];
#pragma unroll
        for (int mt = 0; mt < 4; ++mt)
          a[mt] = *(const bf16x8*)(h_cur + (mt * 16 + ln) * LROW + krel);
        bf16x8 br = *(const bf16x8*)(wrow + krel);
        bf16x8 bz = *(const bf16x8*)(wrow + 512 * 512 + krel);
        bf16x8 bn = *(const bf16x8*)(wrow + 1024 * 512 + krel);
#pragma unroll
        for (int mt = 0; mt < 4; ++mt) {
          accr[mt] = MFMA(a[mt], br, accr[mt]);
          accz[mt] = MFMA(a[mt], bz, accz[mt]);
          acchn[mt] = MFMA(a[mt], bn, acchn[mt]);
        }
      }

      // epilogue: prefetched xp + nonlinearity; write to the OTHER buffer
#pragma unroll
      for (int mt = 0; mt < 4; ++mt)
#pragma unroll
        for (int j = 0; j < 4; ++j) {
          const int row = mt * 16 + ks * 4 + j;
          float xr = bf2f(xr4[mt][j]);
          float xz = bf2f(xz4[mt][j]);
          float xn = bf2f(xn4[mt][j]);
          float rr = sigm(accr[mt][j] + xr);
          float zz = sigm(accz[mt][j] + xz);
          float nn = tanh_(xn + rr * (acchn[mt][j] + b_hn[p]));
          float hold = bf2f(h_cur[row * LROW + dcol]);
          float hnew = (t < len_s[row]) ? ((1.f - zz) * nn + zz * hold) : hold;
          h_nxt[row * LROW + dcol] = f2bf(hnew);
        }
    }  // passes
    __syncthreads();  // h_nxt complete before it becomes h_cur
  }    // t

  // ---- write final h to hcat[s][dir*512 + k] ----
  const u16* hf = (bmax & 1) ? hb1 : hb0;
  const int xrow = tid >> 4;   // 0..63
  const int xcol = tid & 15;   // 0..15
#pragma unroll
  for (int i = 0; i < 4; ++i) {
    int off = (i * 16 + xcol) * 8;
    u16x8 v = *(const u16x8*)(hf + xrow * LROW + off);
    __builtin_nontemporal_store(
        v, (u16x8*)(hcat + (size_t)(s0 + xrow) * 1024 + dir * 512 + off));
  }
}

// ---------------------------------------------------------------------------
// FALLBACK path (ws too small): round-2 fused kernel.
// ---------------------------------------------------------------------------
__global__ __launch_bounds__(256) void build_wcat(const float* __restrict__ Whh,
                                                  const float* __restrict__ Wih,
                                                  u16* __restrict__ Wcat) {
  int i = blockIdx.x * 256 + threadIdx.x;
  if (i >= 1536 * 1024 / 8) return;
  int e = i * 8;
  int g = e >> 10, k = e & 1023;
  const float* src = (k < 512) ? (Whh + g * 512 + k) : (Wih + g * 512 + (k - 512));
  u16x8 o;
#pragma unroll
  for (int j = 0; j < 8; ++j) o[j] = f2bf(src[j]);
  *(u16x8*)(Wcat + e) = o;
}

__global__ __launch_bounds__(512)
__attribute__((amdgpu_waves_per_eu(2, 2))) void gru_persistent(
    const float* __restrict__ win, const int* __restrict__ wlen,
    const u16* __restrict__ Wcat_f, const u16* __restrict__ Wcat_b,
    const float* __restrict__ bih_f, const float* __restrict__ bhh_f,
    const float* __restrict__ bih_b, const float* __restrict__ bhh_b,
    u16* __restrict__ hcat) {
  extern __shared__ char smem[];
  u16* h_s = (u16*)smem;
  u16* x_s = (u16*)(smem + 64 * LROW * 2);
  int* len_s = (int*)(smem + 2 * 64 * LROW * 2);
  int* bmax_s = len_s + 64;

  const int dir = blockIdx.x & 1;
  const int grp = blockIdx.x >> 1;
  const int s0 = grp * 64;
  const u16* W = dir ? Wcat_b : Wcat_f;
  const float* bih = dir ? bih_b : bih_f;
  const float* bhh = dir ? bhh_b : bhh_f;

  const int tid = threadIdx.x;
  const int wave = tid >> 6;
  const int lane = tid & 63;
  const int ln = lane & 15;
  const int ks = lane >> 4;

  if (tid == 0) *bmax_s = 0;
  for (int i = tid; i < 64 * LROW / 8; i += 512) ((u16x8*)h_s)[i] = (u16x8)0;
  __syncthreads();
  if (tid < 64) {
    int wl = wlen[s0 + tid];
    int len = dir ? (wl / 2 + 1) : ((wl - 1) / 2 + 1);
    len_s[tid] = len;
    atomicMax(bmax_s, len);
  }
  __syncthreads();
  const int bmax = *bmax_s;

  float b_r[4], b_z[4], b_xn[4], b_hn[4];
#pragma unroll
  for (int p = 0; p < 4; ++p) {
    int d = (p * 8 + wave) * 16 + ln;
    b_r[p] = bih[d] + bhh[d];
    b_z[p] = bih[512 + d] + bhh[512 + d];
    b_xn[p] = bih[1024 + d];
    b_hn[p] = bhh[1024 + d];
  }

  const int xrow = tid >> 3;
  const int xcol = tid & 7;
  const int mylen = len_s[xrow];
  const long xbase = (long)(s0 + xrow) * 15 + (dir ? (6 + mylen) : (8 - mylen));

  for (int t = 0; t < bmax; ++t) {
    {
      long rowidx = dir ? (xbase - t) : (xbase + t);
      const float* src = win + rowidx * 512;
      u16* dst = x_s + xrow * LROW;
#pragma unroll
      for (int i = 0; i < 8; ++i) {
        int off = xcol * 8 + i * 64;
        f32x4 v0 = *(const f32x4*)(src + off);
        f32x4 v1 = *(const f32x4*)(src + off + 4);
        u16x8 o;
        o[0] = f2bf(v0[0]); o[1] = f2bf(v0[1]); o[2] = f2bf(v0[2]); o[3] = f2bf(v0[3]);
        o[4] = f2bf(v1[0]); o[5] = f2bf(v1[1]); o[6] = f2bf(v1[2]); o[7] = f2bf(v1[3]);
        *(u16x8*)(dst + off) = o;
      }
    }
    __syncthreads();

    unsigned holdp[3][4][2];

#pragma unroll
    for (int p = 0; p < 4; ++p) {
      const int dcol = (p * 8 + wave) * 16 + ln;
      const u16* wrow = W + (size_t)dcol * 1024;

      f32x4 accr[4], accz[4], acchn[4], accxn[4];
#pragma unroll
      for (int mt = 0; mt < 4; ++mt)
#pragma unroll
        for (int j = 0; j < 4; ++j) {
          accr[mt][j] = 0.f; accz[mt][j] = 0.f;
          acchn[mt][j] = 0.f; accxn[mt][j] = 0.f;
        }

#pragma unroll
      for (int kk = 0; kk < 16; ++kk) {
        const int krel = kk * 32 + ks * 8;
        bf16x8 a[4];
#pragma unroll
        for (int mt = 0; mt < 4; ++mt)
          a[mt] = *(const bf16x8*)(h_s + (mt * 16 + ln) * LROW + krel);
        bf16x8 br = *(const bf16x8*)(wrow + krel);
        bf16x8 bz = *(const bf16x8*)(wrow + 512 * 1024 + krel);
        bf16x8 bn = *(const bf16x8*)(wrow + 1024 * 1024 + krel);
#pragma unroll
        for (int mt = 0; mt < 4; ++mt) {
          accr[mt] = MFMA(a[mt], br, accr[mt]);
          accz[mt] = MFMA(a[mt], bz, accz[mt]);
          acchn[mt] = MFMA(a[mt], bn, acchn[mt]);
        }
      }
#pragma unroll
      for (int kk = 0; kk < 16; ++kk) {
        const int krel = kk * 32 + ks * 8;
        bf16x8 a[4];
#pragma unroll
        for (int mt = 0; mt < 4; ++mt)
          a[mt] = *(const bf16x8*)(x_s + (mt * 16 + ln) * LROW + krel);
        bf16x8 br = *(const bf16x8*)(wrow + 512 + krel);
        bf16x8 bz = *(const bf16x8*)(wrow + 512 * 1024 + 512 + krel);
        bf16x8 bn = *(const bf16x8*)(wrow + 1024 * 1024 + 512 + krel);
#pragma unroll
        for (int mt = 0; mt < 4; ++mt) {
          accr[mt] = MFMA(a[mt], br, accr[mt]);
          accz[mt] = MFMA(a[mt], bz, accz[mt]);
          accxn[mt] = MFMA(a[mt], bn, accxn[mt]);
        }
      }

      if (p < 3) {
#pragma unroll
        for (int mt = 0; mt < 4; ++mt)
#pragma unroll
          for (int jp = 0; jp < 2; ++jp) {
            unsigned pk = 0;
#pragma unroll
            for (int jh = 0; jh < 2; ++jh) {
              const int j = jp * 2 + jh;
              const int row = mt * 16 + ks * 4 + j;
              float rr = sigm(accr[mt][j] + b_r[p]);
              float zz = sigm(accz[mt][j] + b_z[p]);
              float nn = tanh_(accxn[mt][j] + b_xn[p] +
                               rr * (acchn[mt][j] + b_hn[p]));
              float hold = bf2f(h_s[row * LROW + dcol]);
              float hnew = (t < len_s[row]) ? ((1.f - zz) * nn + zz * hold) : hold;
              pk |= ((unsigned)f2bf(hnew)) << (16 * jh);
            }
            holdp[p][mt][jp] = pk;
          }
      } else {
        __syncthreads();
#pragma unroll
        for (int pp = 0; pp < 3; ++pp) {
          const int dd = (pp * 8 + wave) * 16 + ln;
#pragma unroll
          for (int mt = 0; mt < 4; ++mt)
#pragma unroll
            for (int jp = 0; jp < 2; ++jp) {
              unsigned pk = holdp[pp][mt][jp];
              const int row = mt * 16 + ks * 4 + jp * 2;
              h_s[row * LROW + dd] = (u16)pk;
              h_s[(row + 1) * LROW + dd] = (u16)(pk >> 16);
            }
        }
#pragma unroll
        for (int mt = 0; mt < 4; ++mt)
#pragma unroll
          for (int j = 0; j < 4; ++j) {
            const int row = mt * 16 + ks * 4 + j;
            float rr = sigm(accr[mt][j] + b_r[3]);
            float zz = sigm(accz[mt][j] + b_z[3]);
            float nn = tanh_(accxn[mt][j] + b_xn[3] +
                             rr * (acchn[mt][j] + b_hn[3]));
            float hold = bf2f(h_s[row * LROW + dcol]);
            float hnew = (t < len_s[row]) ? ((1.f - zz) * nn + zz * hold) : hold;
            h_s[row * LROW + dcol] = f2bf(hnew);
          }
      }
    }
  }

  __syncthreads();
#pragma unroll
  for (int i = 0; i < 8; ++i) {
    int off = xcol * 8 + i * 64;
    u16x8 v = *(const u16x8*)(h_s + xrow * LROW + off);
    __builtin_nontemporal_store(
        v, (u16x8*)(hcat + (size_t)(s0 + xrow) * 1024 + dir * 512 + off));
  }
}

// ---------------------------------------------------------------------------
// MLP GEMM: out[M,N] = act(A[M,K] @ Bw[N,K]^T + bias)
// ---------------------------------------------------------------------------
__global__ __launch_bounds__(256) void mlp_gemm(const u16* __restrict__ A,
                                                const u16* __restrict__ Bw,
                                                const float* __restrict__ bias,
                                                void* __restrict__ out, int M,
                                                int N, int K, int mode) {
  __shared__ u16 As[128 * 64], Bs[128 * 64];
  const int tid = threadIdx.x;
  const int wave = tid >> 6, lane = tid & 63;
  const int ln = lane & 15, ks = lane >> 4;
  const int wm = wave & 1, wn = wave >> 1;
  const int m0 = blockIdx.x * 128, n0 = blockIdx.y * 128;
  f32x4 acc[4][4];
#pragma unroll
  for (int mt = 0; mt < 4; ++mt)
#pragma unroll
    for (int nt = 0; nt < 4; ++nt)
#pragma unroll
      for (int j = 0; j < 4; ++j) acc[mt][nt][j] = 0.f;

  const int r = tid >> 1, hh = tid & 1;
  for (int k0 = 0; k0 < K; k0 += 64) {
    const i32x4* sa = (const i32x4*)(A + (size_t)(m0 + r) * K + k0 + hh * 32);
    const i32x4* sb = (const i32x4*)(Bw + (size_t)(n0 + r) * K + k0 + hh * 32);
    i32x4* da = (i32x4*)(As + r * 64 + hh * 32);
    i32x4* db = (i32x4*)(Bs + r * 64 + hh * 32);
#pragma unroll
    for (int i = 0; i < 4; ++i) da[i] = sa[i];
#pragma unroll
    for (int i = 0; i < 4; ++i) db[i] = sb[i];
    __syncthreads();
#pragma unroll
    for (int kk = 0; kk < 2; ++kk) {
      bf16x8 af[4], bfm[4];
#pragma unroll
      for (int mt = 0; mt < 4; ++mt)
        af[mt] = *(const bf16x8*)(As + (wm * 64 + mt * 16 + ln) * 64 + kk * 32 + ks * 8);
#pragma unroll
      for (int nt = 0; nt < 4; ++nt)
        bfm[nt] = *(const bf16x8*)(Bs + (wn * 64 + nt * 16 + ln) * 64 + kk * 32 + ks * 8);
#pragma unroll
      for (int mt = 0; mt < 4; ++mt)
#pragma unroll
        for (int nt = 0; nt < 4; ++nt) acc[mt][nt] = MFMA(af[mt], bfm[nt], acc[mt][nt]);
    }
    __syncthreads();
  }

#pragma unroll
  for (int nt = 0; nt < 4; ++nt) {
    int col = n0 + wn * 64 + nt * 16 + ln;
    float bv = bias[col];
#pragma unroll
    for (int mt = 0; mt < 4; ++mt)
#pragma unroll
      for (int j = 0; j < 4; ++j) {
        int row = m0 + wm * 64 + mt * 16 + ks * 4 + j;
        float v = acc[mt][nt][j] + bv;
        if (mode) {
          v = fmaxf(v, 0.f);
          ((u16*)out)[(size_t)row * N + col] = f2bf(v);
        } else {
          ((float*)out)[(size_t)row * N + col] = v;
        }
      }
  }
}

// ---------------------------------------------------------------------------
extern "C" void kernel_launch(void* const* d_in, const int* in_sizes, int n_in,
                              void* d_out, int out_size, void* d_ws, size_t ws_size,
                              hipStream_t stream) {
  (void)in_sizes; (void)n_in; (void)out_size;
  const float* win = (const float*)d_in[0];
  const int* wlen = (const int*)d_in[1];
  const float* Wih_f = (const float*)d_in[2];
  const float* Whh_f = (const float*)d_in[3];
  const float* bih_f = (const float*)d_in[4];
  const float* bhh_f = (const float*)d_in[5];
  const float* Wih_b = (const float*)d_in[6];
  const float* Whh_b = (const float*)d_in[7];
  const float* bih_b = (const float*)d_in[8];
  const float* bhh_b = (const float*)d_in[9];
  const float* W1 = (const float*)d_in[10];
  const float* b1 = (const float*)d_in[11];
  const float* W2 = (const float*)d_in[12];
  const float* b2 = (const float*)d_in[13];

  const size_t NEED = 4ull * 1572864 + 1048576 + 524288 + 16777216 + 8388608 +
                      402653184ull;  // = 435,683,328

  if (ws_size >= NEED) {
    char* ws = (char*)d_ws;
    u16* Whhb_f = (u16*)ws; ws += 1572864;
    u16* Whhb_b = (u16*)ws; ws += 1572864;
    u16* Wihb_f = (u16*)ws; ws += 1572864;
    u16* Wihb_b = (u16*)ws; ws += 1572864;
    u16* W1b = (u16*)ws;    ws += 1048576;
    u16* W2b = (u16*)ws;    ws += 524288;
    u16* hcat = (u16*)ws;   ws += 16777216;
    u16* hidden = (u16*)ws; ws += 8388608;
    u16* xp = (u16*)ws;     ws += 402653184;

    cvt_bf16<<<384, 256, 0, stream>>>(Whh_f, Whhb_f, 98304);
    cvt_bf16<<<384, 256, 0, stream>>>(Whh_b, Whhb_b, 98304);
    cvt_bf16<<<384, 256, 0, stream>>>(Wih_f, Wihb_f, 98304);
    cvt_bf16<<<384, 256, 0, stream>>>(Wih_b, Wihb_b, 98304);
    cvt_bf16<<<256, 256, 0, stream>>>(W1, W1b, 65536);
    cvt_bf16<<<128, 256, 0, stream>>>(W2, W2b, 32768);

    const int SMEM_XP = 128 * LROWA * 2;  // 133,120 B
    (void)hipFuncSetAttribute((const void*)xp_gemm,
                              hipFuncAttributeMaxDynamicSharedMemorySize, SMEM_XP);
    xp_gemm<<<dim3(512, 2), 256, SMEM_XP, stream>>>(
        win, wlen, Wihb_f, Wihb_b, bih_f, bih_b, bhh_f, bhh_b, xp);

    const int SMEM = 2 * 64 * LROW * 2 + 64 * 4 + 16;
    (void)hipFuncSetAttribute((const void*)gru_rec,
                              hipFuncAttributeMaxDynamicSharedMemorySize, SMEM);
    gru_rec<<<256, 1024, SMEM, stream>>>(wlen, Whhb_f, Whhb_b, bhh_f, bhh_b, xp,
                                         hcat);

    mlp_gemm<<<dim3(64, 4), 256, 0, stream>>>(hcat, W1b, b1, hidden, 8192, 512, 1024, 1);
    mlp_gemm<<<dim3(64, 4), 256, 0, stream>>>(hidden, W2b, b2, d_out, 8192, 512, 512, 0);
  } else {
    char* ws = (char*)d_ws;
    u16* Wcat_f = (u16*)ws;  ws += 3145728;
    u16* Wcat_b = (u16*)ws;  ws += 3145728;
    u16* W1b = (u16*)ws;     ws += 1048576;
    u16* W2b = (u16*)ws;     ws += 524288;
    u16* hcat = (u16*)ws;    ws += 16777216;
    u16* hidden = (u16*)ws;  ws += 8388608;

    build_wcat<<<768, 256, 0, stream>>>(Whh_f, Wih_f, Wcat_f);
    build_wcat<<<768, 256, 0, stream>>>(Whh_b, Wih_b, Wcat_b);
    cvt_bf16<<<256, 256, 0, stream>>>(W1, W1b, 65536);
    cvt_bf16<<<128, 256, 0, stream>>>(W2, W2b, 32768);

    const int SMEM = 2 * 64 * LROW * 2 + 64 * 4 + 16;
    (void)hipFuncSetAttribute((const void*)gru_persistent,
                              hipFuncAttributeMaxDynamicSharedMemorySize, SMEM);
    gru_persistent<<<256, 512, SMEM, stream>>>(win, wlen, Wcat_f, Wcat_b, bih_f,
                                               bhh_f, bih_b, bhh_b, hcat);

    mlp_gemm<<<dim3(64, 4), 256, 0, stream>>>(hcat, W1b, b1, hidden, 8192, 512, 1024, 1);
    mlp_gemm<<<dim3(64, 4), 256, 0, stream>>>(hidden, W2b, b2, d_out, 8192, 512, 512, 0);
  }
}